// Round 3
// baseline (356.008 us; speedup 1.0000x reference)
//
#include <hip/hip_runtime.h>
#include <cstdint>
#include <cstddef>

// ---------------------------------------------------------------------------
// GCN 2-layer, N=100k nodes, E=1.6M edges, F=64, fp32 in/out.
//
//   dis[n] = rsqrt(in_deg[n]+1)            (self-loop folded in analytically)
//   g = bf16( (X @ W) * dis[row] )
//   out[n] = dis[n] * ( sum_{e: dst=n} g[src(e)] + g[n] ) + b   (+ relu L1)
//
// CSR build: bucketed counting sort (512-node buckets, L2-resident windows).
// Bucket bases allocated by atomicAdd (order-free) -> no global scan kernel.
// Aggregation: 4 nodes per wave, 16 lanes x uint2 (4 bf16 feats) per node,
// 16-deep unrolled gather chunk -> 16 rows (2 KB) in flight per wave.
// ---------------------------------------------------------------------------

#define BK_SHIFT 9                // 512 nodes per bucket
#define BK_NODES 512
#define EPB 8192                  // edges per scatter block

static __device__ __forceinline__ unsigned short f2b(float f) {
    unsigned x = __float_as_uint(f);
    unsigned r = (x + 0x7FFFu + ((x >> 16) & 1u)) >> 16;   // RNE
    return (unsigned short)r;
}
static __device__ __forceinline__ float blo(unsigned u) {
    return __uint_as_float(u << 16);
}
static __device__ __forceinline__ float bhi(unsigned u) {
    return __uint_as_float(u & 0xFFFF0000u);
}

// ---- Pass A: bucket histogram (LDS hist per block -> global atomic) -------
__global__ void __launch_bounds__(256) k_bhist(const int* __restrict__ dst,
                                               int* __restrict__ bcnt, int E, int NB) {
    __shared__ int hist[1024];
    for (int i = threadIdx.x; i < NB; i += 256) hist[i] = 0;
    __syncthreads();
    int stride = gridDim.x * 256;
    for (int e = blockIdx.x * 256 + threadIdx.x; e < E; e += stride)
        atomicAdd(&hist[dst[e] >> BK_SHIFT], 1);
    __syncthreads();
    for (int i = threadIdx.x; i < NB; i += 256) {
        int c = hist[i];
        if (c) atomicAdd(&bcnt[i], c);
    }
}

// ---- Pass B: order-free bucket base allocation (bcnt[NB] is the counter) --
__global__ void __launch_bounds__(256) k_alloc(int* __restrict__ bcnt,
                                               int* __restrict__ bbase,
                                               int* __restrict__ gcursor, int NB) {
    int t = threadIdx.x;
    if (t < NB) {
        int c = bcnt[t];
        int b = atomicAdd(&bcnt[NB], c);
        bbase[t] = b;
        gcursor[t] = b;
    }
}

// ---- Pass C: scatter edges into bucket-ordered store, packed uint32 -------
// pack = src (17 bits) | dst_local (9 bits) << 17   (N <= 131072)
__global__ void __launch_bounds__(256) k_bscatter(const int* __restrict__ src,
                                                  const int* __restrict__ dst,
                                                  int* __restrict__ gcursor,
                                                  unsigned* __restrict__ packed,
                                                  int E, int NB) {
    __shared__ int hist[1024];
    __shared__ int base[1024];
    for (int i = threadIdx.x; i < NB; i += 256) hist[i] = 0;
    __syncthreads();
    int e0 = blockIdx.x * EPB;
    int e1 = min(e0 + EPB, E);
    for (int e = e0 + threadIdx.x; e < e1; e += 256)
        atomicAdd(&hist[dst[e] >> BK_SHIFT], 1);
    __syncthreads();
    for (int i = threadIdx.x; i < NB; i += 256) {
        int c = hist[i];
        base[i] = c ? atomicAdd(&gcursor[i], c) : 0;
        hist[i] = 0;
    }
    __syncthreads();
    for (int e = e0 + threadIdx.x; e < e1; e += 256) {
        int d = dst[e];
        int s = src[e];
        int bkt = d >> BK_SHIFT;
        int pos = base[bkt] + atomicAdd(&hist[bkt], 1);
        packed[pos] = (unsigned)s | (((unsigned)d & (BK_NODES - 1)) << 17);
    }
}

// ---- Pass D: per-bucket CSR build (one block per bucket, local windows) ---
__global__ void __launch_bounds__(512) k_build(const unsigned* __restrict__ packed,
                                               const int* __restrict__ bbase,
                                               const int* __restrict__ bcnt,
                                               int* __restrict__ rp,
                                               int* __restrict__ dega,
                                               float* __restrict__ dis,
                                               int* __restrict__ col, int N) {
    __shared__ int cnt_s[BK_NODES];
    __shared__ int tmp[BK_NODES];
    int b = blockIdx.x;
    int t = threadIdx.x;
    int node0 = b << BK_SHIFT;
    int nnode = min(BK_NODES, N - node0);
    int e0 = bbase[b];
    int e1 = e0 + bcnt[b];
    cnt_s[t] = 0;
    __syncthreads();
    for (int e = e0 + t; e < e1; e += 512)
        atomicAdd(&cnt_s[packed[e] >> 17], 1);
    __syncthreads();
    int v = cnt_s[t];
    tmp[t] = v;
    __syncthreads();
    for (int off = 1; off < BK_NODES; off <<= 1) {
        int a = (t >= off) ? tmp[t - off] : 0;
        __syncthreads();
        tmp[t] += a;
        __syncthreads();
    }
    int excl = tmp[t] - v;
    if (t < nnode) {
        rp[node0 + t] = e0 + excl;
        dega[node0 + t] = v;
        dis[node0 + t] = rsqrtf((float)(v + 1));
    }
    __syncthreads();
    cnt_s[t] = excl;               // reuse as local cursor
    __syncthreads();
    for (int e = e0 + t; e < e1; e += 512) {
        unsigned p = packed[e];
        int dl = (int)(p >> 17);
        int pos = atomicAdd(&cnt_s[dl], 1);
        col[e0 + pos] = (int)(p & 0x1FFFFu);
    }
}

// ---- GEMM: g16[row] = bf16( (X[row] @ W) * dis[row] ) ---------------------
// Thread-per-row; all 16 x float4 loads hoisted; W via float4 broadcast loads.
__global__ void __launch_bounds__(256) k_gemm64(const float* __restrict__ X,
                                                const float* __restrict__ W,
                                                const float* __restrict__ dis,
                                                unsigned short* __restrict__ g16, int n) {
    int row = blockIdx.x * 256 + threadIdx.x;
    if (row >= n) return;
    const float4* xr = (const float4*)(X + ((size_t)row << 6));
    float4 xv[16];
#pragma unroll
    for (int k4 = 0; k4 < 16; ++k4) xv[k4] = xr[k4];
    float acc[64];
#pragma unroll
    for (int j = 0; j < 64; ++j) acc[j] = 0.f;
    const float4* W4 = (const float4*)W;
#pragma unroll
    for (int k = 0; k < 64; ++k) {
        float xk = ((const float*)xv)[k];
#pragma unroll
        for (int j4 = 0; j4 < 16; ++j4) {
            float4 w = W4[k * 16 + j4];
            acc[j4 * 4 + 0] = fmaf(xk, w.x, acc[j4 * 4 + 0]);
            acc[j4 * 4 + 1] = fmaf(xk, w.y, acc[j4 * 4 + 1]);
            acc[j4 * 4 + 2] = fmaf(xk, w.z, acc[j4 * 4 + 2]);
            acc[j4 * 4 + 3] = fmaf(xk, w.w, acc[j4 * 4 + 3]);
        }
    }
    float s = dis[row];
    uint4* o = (uint4*)(g16 + ((size_t)row << 6));
#pragma unroll
    for (int j8 = 0; j8 < 8; ++j8) {
        uint4 p;
        p.x = (unsigned)f2b(acc[j8 * 8 + 0] * s) | ((unsigned)f2b(acc[j8 * 8 + 1] * s) << 16);
        p.y = (unsigned)f2b(acc[j8 * 8 + 2] * s) | ((unsigned)f2b(acc[j8 * 8 + 3] * s) << 16);
        p.z = (unsigned)f2b(acc[j8 * 8 + 4] * s) | ((unsigned)f2b(acc[j8 * 8 + 5] * s) << 16);
        p.w = (unsigned)f2b(acc[j8 * 8 + 6] * s) | ((unsigned)f2b(acc[j8 * 8 + 7] * s) << 16);
        o[j8] = p;
    }
}

// ---- Aggregate: 4 nodes/wave, 16 lanes/node, uint2 = 4 bf16 feats/lane ----
template <int RELU>
__global__ void __launch_bounds__(256) k_agg(const unsigned short* __restrict__ g16,
                                             const int* __restrict__ col,
                                             const int* __restrict__ rp,
                                             const int* __restrict__ dega,
                                             const float* __restrict__ dis,
                                             const float* __restrict__ bias,
                                             float* __restrict__ out, int n) {
    int lane = threadIdx.x & 63;
    int wv = (blockIdx.x << 2) | (threadIdx.x >> 6);   // global wave id
    int sub = lane >> 4;
    int fl = lane & 15;
    int base = wv << 2;
    if (base >= n) return;                              // wave-uniform
    int node = base + sub;
    int nd = min(node, n - 1);
    int start = rp[nd];
    int deg = (node < n) ? dega[nd] : 0;
    int dm = max(deg, __shfl_xor(deg, 16));
    dm = max(dm, __shfl_xor(dm, 32));                   // wave max deg

    uint2 us = *((const uint2*)(g16 + ((size_t)nd << 6)) + fl);   // self row
    float A0 = blo(us.x), A1 = bhi(us.x), A2 = blo(us.y), A3 = bhi(us.y);
    float B0 = 0.f, B1 = 0.f, B2 = 0.f, B3 = 0.f;

    int sb = sub << 4;
    for (int c = 0; c < dm; c += 16) {
        int rem = deg - c;
        int cv = 0;
        if (fl < rem) cv = col[start + c + fl];
#pragma unroll
        for (int i = 0; i < 16; i += 2) {
            int r0 = __shfl(cv, sb + i);
            int r1 = __shfl(cv, sb + i + 1);
            if (i < rem) {
                uint2 u = *((const uint2*)(g16 + ((size_t)r0 << 6)) + fl);
                A0 += blo(u.x); A1 += bhi(u.x); A2 += blo(u.y); A3 += bhi(u.y);
            }
            if (i + 1 < rem) {
                uint2 u = *((const uint2*)(g16 + ((size_t)r1 << 6)) + fl);
                B0 += blo(u.x); B1 += bhi(u.x); B2 += blo(u.y); B3 += bhi(u.y);
            }
        }
    }
    float s = dis[nd];
    float4 bv = ((const float4*)bias)[fl];
    float4 r;
    r.x = fmaf(s, A0 + B0, bv.x);
    r.y = fmaf(s, A1 + B1, bv.y);
    r.z = fmaf(s, A2 + B2, bv.z);
    r.w = fmaf(s, A3 + B3, bv.w);
    if (RELU) {
        r.x = fmaxf(r.x, 0.f); r.y = fmaxf(r.y, 0.f);
        r.z = fmaxf(r.z, 0.f); r.w = fmaxf(r.w, 0.f);
    }
    if (node < n)
        *((float4*)(out + ((size_t)node << 6)) + fl) = r;
}

extern "C" void kernel_launch(void* const* d_in, const int* in_sizes, int n_in,
                              void* d_out, int out_size, void* d_ws, size_t ws_size,
                              hipStream_t stream) {
    const float* x  = (const float*)d_in[0];
    const int*   ei = (const int*)d_in[1];
    const float* W1 = (const float*)d_in[2];
    const float* b1 = (const float*)d_in[3];
    const float* W2 = (const float*)d_in[4];
    const float* b2 = (const float*)d_in[5];
    float* out = (float*)d_out;

    const int N = in_sizes[0] / 64;
    const int E = in_sizes[1] / 2;
    const int NB = (N + BK_NODES - 1) >> BK_SHIFT;
    const int* src = ei;
    const int* dst = ei + E;

    char* ws = (char*)d_ws;
    size_t off = 0;
    auto alloc = [&](size_t bytes) -> void* {
        void* p = ws + off;
        off = (off + bytes + 255) & ~(size_t)255;
        return p;
    };
    int*            bcnt    = (int*)alloc((size_t)(NB + 1) * 4);   // [NB] = alloc counter
    int*            bbase   = (int*)alloc((size_t)NB * 4);
    int*            gcursor = (int*)alloc((size_t)NB * 4);
    int*            rp      = (int*)alloc((size_t)N * 4);
    int*            dega    = (int*)alloc((size_t)N * 4);
    float*          dis     = (float*)alloc((size_t)N * 4);
    unsigned*       packed  = (unsigned*)alloc((size_t)E * 4);
    int*            col     = (int*)alloc((size_t)E * 4);
    unsigned short* g16     = (unsigned short*)alloc((size_t)N * 64 * 2);
    float*          h       = (float*)alloc((size_t)N * 64 * 4);
    (void)ws_size;

    hipMemsetAsync(bcnt, 0, (size_t)(NB + 1) * 4, stream);
    k_bhist<<<512, 256, 0, stream>>>(dst, bcnt, E, NB);
    k_alloc<<<1, 256, 0, stream>>>(bcnt, bbase, gcursor, NB);
    k_bscatter<<<(E + EPB - 1) / EPB, 256, 0, stream>>>(src, dst, gcursor, packed, E, NB);
    k_build<<<NB, 512, 0, stream>>>(packed, bbase, bcnt, rp, dega, dis, col, N);

    const int tb = 256;
    // Layer 1
    k_gemm64<<<(N + tb - 1) / tb, tb, 0, stream>>>(x, W1, dis, g16, N);
    k_agg<1><<<(N + 15) / 16, 256, 0, stream>>>(g16, col, rp, dega, dis, b1, h, N);
    // Layer 2
    k_gemm64<<<(N + tb - 1) / tb, tb, 0, stream>>>(h, W2, dis, g16, N);
    k_agg<0><<<(N + 15) / 16, 256, 0, stream>>>(g16, col, rp, dega, dis, b2, out, N);
}